// Round 6
// baseline (322.497 us; speedup 1.0000x reference)
//
#include <hip/hip_runtime.h>
#include <hip/hip_bf16.h>

#define U_ 2048
#define T_ 512
#define K_ 128
#define B_ 32
#define RHO_ 0.99f

typedef __attribute__((ext_vector_type(8))) short short8;
typedef __attribute__((ext_vector_type(4))) float f32x4;

__device__ __forceinline__ float fast_tanh(float x) {
  float e = __expf(2.0f * x);          // inf for large x -> returns +/-1 correctly
  return 1.0f - 2.0f / (e + 1.0f);
}

__device__ __forceinline__ unsigned short bf16_rne(float x) {
  unsigned int u = __float_as_uint(x);
  u += 0x7FFFu + ((u >> 16) & 1u);
  return (unsigned short)(u >> 16);
}

// ---------------- converts ----------------
// A [16384][128] fp32 -> Ab [16384][256] bf16 (k<128: hi, k>=128: lo residual)
__global__ __launch_bounds__(256) void convert_a_kernel(
    const float* __restrict__ A, unsigned short* __restrict__ Ab) {
  const int gi = blockIdx.x * 256 + threadIdx.x;
  const int m = gi >> 5;          // needs 2048 blocks
  const int kq = (gi & 31) << 2;
  const float4 v = *(const float4*)&A[(size_t)m * K_ + kq];
  ushort4 hi, lo;
  hi.x = bf16_rne(v.x); hi.y = bf16_rne(v.y); hi.z = bf16_rne(v.z); hi.w = bf16_rne(v.w);
  lo.x = bf16_rne(v.x - __uint_as_float((unsigned)hi.x << 16));
  lo.y = bf16_rne(v.y - __uint_as_float((unsigned)hi.y << 16));
  lo.z = bf16_rne(v.z - __uint_as_float((unsigned)hi.z << 16));
  lo.w = bf16_rne(v.w - __uint_as_float((unsigned)hi.w << 16));
  *(ushort4*)&Ab[(size_t)m * 256 + kq] = hi;
  *(ushort4*)&Ab[(size_t)m * 256 + 128 + kq] = lo;
}

// W [128][2048] fp32 -> Wbt [2048][256] bf16 transposed, duplicated along k
__global__ __launch_bounds__(256) void convert_w_kernel(
    const float* __restrict__ W, unsigned short* __restrict__ Wbt) {
  const int gi = blockIdx.x * 256 + threadIdx.x;   // 65536 threads
  const int kq = gi >> 11;        // 0..31
  const int n = gi & 2047;
  const int k = kq << 2;
  ushort4 w;
  w.x = bf16_rne(W[(size_t)(k + 0) * U_ + n]);
  w.y = bf16_rne(W[(size_t)(k + 1) * U_ + n]);
  w.z = bf16_rne(W[(size_t)(k + 2) * U_ + n]);
  w.w = bf16_rne(W[(size_t)(k + 3) * U_ + n]);
  *(ushort4*)&Wbt[(size_t)n * 256 + k] = w;
  *(ushort4*)&Wbt[(size_t)n * 256 + 128 + k] = w;
}

// ---------------- MFMA GEMM v3: VGPR staging + XOR-swizzled unpadded LDS ------
// LDS layout: row stride 64 shorts (128 B = 8 chunks of 16 B, no padding).
// LDS chunk c of row r holds GLOBAL chunk c ^ (r&7).  XOR is a Latin square:
// each consecutive-8-lane group touches all 8 bank quads exactly once for both
// ds_write_b128 staging and ds_read_b128 fragment reads (2-way = free).
__global__ __launch_bounds__(256, 3) void mfma_gemm3_kernel(
    const unsigned short* __restrict__ Ab, const unsigned short* __restrict__ Wbt,
    const float* __restrict__ bias, float* __restrict__ us) {
  __shared__ unsigned short As[128 * 64];   // 16 KB
  __shared__ unsigned short Bs[128 * 64];   // 16 KB
  const int tid = threadIdx.x;
  const int m0 = blockIdx.y << 7;
  const int n0 = blockIdx.x << 7;
  const int wave = tid >> 6;
  const int lane = tid & 63;
  const int r = lane & 15;        // row within 16x16 tile
  const int q = lane >> 4;        // quad
  const int mw = (wave >> 1) << 6;
  const int nw = (wave & 1) << 6;

  f32x4 acc[4][4] = {};

  // staging geometry: wave w stages rows [32w, 32w+32) of A and B, 4 insts each.
  // lane l handles row (l>>3) within the 8-row inst group, global chunk (l&7).
  const int rl8 = lane >> 3;                 // 0..7
  const int cg = lane & 7;                   // global chunk (coalesced)
  const int lchunk = cg ^ rl8;               // swizzled LDS chunk
  const int wrow0 = wave << 5;

  float4 av[4], bv4[4];
  #pragma unroll
  for (int j = 0; j < 4; ++j) {
    const int row = wrow0 + (j << 3) + rl8;
    av[j]  = *(const float4*)&Ab[((size_t)(m0 + row) << 8) + (cg << 3)];
    bv4[j] = *(const float4*)&Wbt[((size_t)(n0 + row) << 8) + (cg << 3)];
  }

  #pragma unroll
  for (int s = 0; s < 4; ++s) {
    if (s) __syncthreads();                  // LDS reads of step s-1 retired
    #pragma unroll
    for (int j = 0; j < 4; ++j) {
      const int row = wrow0 + (j << 3) + rl8;
      *(float4*)&As[(row << 6) + (lchunk << 3)] = av[j];
      *(float4*)&Bs[(row << 6) + (lchunk << 3)] = bv4[j];
    }
    __syncthreads();                         // staging visible

    // issue next step's global loads before compute (overlap latency)
    if (s < 3) {
      const int k0n = (s + 1) << 6;
      #pragma unroll
      for (int j = 0; j < 4; ++j) {
        const int row = wrow0 + (j << 3) + rl8;
        av[j]  = *(const float4*)&Ab[((size_t)(m0 + row) << 8) + k0n + (cg << 3)];
        bv4[j] = *(const float4*)&Wbt[((size_t)(n0 + row) << 8) + k0n + (cg << 3)];
      }
    }

    #pragma unroll
    for (int kk = 0; kk < 2; ++kk) {
      short8 af[4], bf[4];
      #pragma unroll
      for (int i = 0; i < 4; ++i) {
        const int row = mw + (i << 4) + r;
        af[i] = *(const short8*)&As[(row << 6) + ((((kk << 2) + q) ^ (row & 7)) << 3)];
      }
      #pragma unroll
      for (int j2 = 0; j2 < 4; ++j2) {
        const int row = nw + (j2 << 4) + r;
        bf[j2] = *(const short8*)&Bs[(row << 6) + ((((kk << 2) + q) ^ (row & 7)) << 3)];
      }
      #pragma unroll
      for (int i = 0; i < 4; ++i)
        #pragma unroll
        for (int j2 = 0; j2 < 4; ++j2)
          acc[i][j2] = __builtin_amdgcn_mfma_f32_16x16x32_bf16(af[i], bf[j2], acc[i][j2], 0, 0, 0);
    }
  }

  // epilogue: +bias, diagonal-shifted store (D layout: col=lane&15, row=quad*4+reg)
  #pragma unroll
  for (int j = 0; j < 4; ++j) {
    const int n = n0 + nw + (j << 4) + r;
    const float bv = bias[n];
    #pragma unroll
    for (int i = 0; i < 4; ++i) {
      const int mb = m0 + mw + (i << 4) + (q << 2);
      #pragma unroll
      for (int reg = 0; reg < 4; ++reg) {
        const int m = mb + reg;
        const int t = m & (T_ - 1);
        us[((size_t)m << 11) + ((n - t) & (U_ - 1))] = acc[i][j][reg] + bv;
      }
    }
  }
}

// ---------------- scan (separate buffers, shifted reads) ----------------
__global__ __launch_bounds__(256) void ring_scan2_kernel(
    const float* __restrict__ us, const float* __restrict__ h0,
    float* __restrict__ out) {
  const int b = blockIdx.y;
  const int c = (blockIdx.x << 8) + threadIdx.x;
  const float* src = us + (size_t)b * (T_ * U_) + c;   // stride U_ per t
  float* const dst = out + (size_t)b * (T_ * U_);
  float h = h0[((size_t)b << 11) + ((c + U_ - 1) & (U_ - 1))];

  float w0[16], w1[16];
  #pragma unroll
  for (int j = 0; j < 16; ++j) w0[j] = src[(size_t)j << 11];

  for (int t0 = 0; t0 < T_; t0 += 32) {
    #pragma unroll
    for (int j = 0; j < 16; ++j)
      w1[j] = src[(size_t)(t0 + 16 + j) << 11];
    #pragma unroll
    for (int j = 0; j < 16; ++j) {
      const int t = t0 + j;
      h = fast_tanh(fmaf(RHO_, h, w0[j]));
      dst[((size_t)t << 11) + ((c + t) & (U_ - 1))] = h;
    }
    if (t0 + 32 < T_) {
      #pragma unroll
      for (int j = 0; j < 16; ++j)
        w0[j] = src[(size_t)(t0 + 32 + j) << 11];
    }
    #pragma unroll
    for (int j = 0; j < 16; ++j) {
      const int t = t0 + 16 + j;
      h = fast_tanh(fmaf(RHO_, h, w1[j]));
      dst[((size_t)t << 11) + ((c + t) & (U_ - 1))] = h;
    }
  }
}

// ---------------- fallback path (R1, proven correct) ----------------
__global__ __launch_bounds__(256, 4) void gemm_bias_kernel(
    const float* __restrict__ A, const float* __restrict__ W,
    const float* __restrict__ bias, float* __restrict__ out) {
  __shared__ float Asf[64][68];
  __shared__ float Bsf[64][64];
  const int tid = threadIdx.x;
  const int m0 = blockIdx.y << 6;
  const int n0 = blockIdx.x << 6;
  const int tx = tid & 15;
  const int ty = tid >> 4;
  float acc[4][4] = {};
  #pragma unroll
  for (int kb = 0; kb < 2; ++kb) {
    if (kb) __syncthreads();
    {
      const int c4 = tid & 15;
      const int r0 = tid >> 4;
      #pragma unroll
      for (int rr = 0; rr < 4; ++rr) {
        const int r = r0 + (rr << 4);
        const float4 v = *(const float4*)(A + (size_t)(m0 + r) * K_ + (kb << 6) + (c4 << 2));
        Asf[(c4 << 2) + 0][r] = v.x;
        Asf[(c4 << 2) + 1][r] = v.y;
        Asf[(c4 << 2) + 2][r] = v.z;
        Asf[(c4 << 2) + 3][r] = v.w;
      }
    }
    {
      const int c4 = tid & 15;
      const int r0 = tid >> 4;
      #pragma unroll
      for (int rr = 0; rr < 4; ++rr) {
        const int k = r0 + (rr << 4);
        *(float4*)&Bsf[k][c4 << 2] =
            *(const float4*)(W + (size_t)((kb << 6) + k) * U_ + n0 + (c4 << 2));
      }
    }
    __syncthreads();
    #pragma unroll 16
    for (int k = 0; k < 64; ++k) {
      const float4 a = *(const float4*)&Asf[k][ty << 2];
      const float4 b = *(const float4*)&Bsf[k][tx << 2];
      acc[0][0] = fmaf(a.x, b.x, acc[0][0]); acc[0][1] = fmaf(a.x, b.y, acc[0][1]);
      acc[0][2] = fmaf(a.x, b.z, acc[0][2]); acc[0][3] = fmaf(a.x, b.w, acc[0][3]);
      acc[1][0] = fmaf(a.y, b.x, acc[1][0]); acc[1][1] = fmaf(a.y, b.y, acc[1][1]);
      acc[1][2] = fmaf(a.y, b.z, acc[1][2]); acc[1][3] = fmaf(a.y, b.w, acc[1][3]);
      acc[2][0] = fmaf(a.z, b.x, acc[2][0]); acc[2][1] = fmaf(a.z, b.y, acc[2][1]);
      acc[2][2] = fmaf(a.z, b.z, acc[2][2]); acc[2][3] = fmaf(a.z, b.w, acc[2][3]);
      acc[3][0] = fmaf(a.w, b.x, acc[3][0]); acc[3][1] = fmaf(a.w, b.y, acc[3][1]);
      acc[3][2] = fmaf(a.w, b.z, acc[3][2]); acc[3][3] = fmaf(a.w, b.w, acc[3][3]);
    }
  }
  const float4 bv = *(const float4*)(bias + n0 + (tx << 2));
  #pragma unroll
  for (int i = 0; i < 4; ++i) {
    float4 o;
    o.x = acc[i][0] + bv.x; o.y = acc[i][1] + bv.y;
    o.z = acc[i][2] + bv.z; o.w = acc[i][3] + bv.w;
    *(float4*)(out + (size_t)(m0 + (ty << 2) + i) * U_ + n0 + (tx << 2)) = o;
  }
}

__global__ __launch_bounds__(256) void ring_scan_kernel(
    float* __restrict__ buf, const float* __restrict__ h0) {
  const int b = blockIdx.y;
  const int c = (blockIdx.x << 8) + threadIdx.x;
  float* const base = buf + (size_t)b * (T_ * U_);
  float h = h0[((size_t)b << 11) + ((c + U_ - 1) & (U_ - 1))];
  float wA[8], wB[8];
  #pragma unroll
  for (int j = 0; j < 8; ++j)
    wA[j] = base[((size_t)j << 11) + ((c + j) & (U_ - 1))];
  for (int t0 = 0; t0 < T_; t0 += 16) {
    #pragma unroll
    for (int j = 0; j < 8; ++j) {
      const int t = t0 + 8 + j;
      wB[j] = base[((size_t)t << 11) + ((c + t) & (U_ - 1))];
    }
    #pragma unroll
    for (int j = 0; j < 8; ++j) {
      const int t = t0 + j;
      h = fast_tanh(fmaf(RHO_, h, wA[j]));
      base[((size_t)t << 11) + ((c + t) & (U_ - 1))] = h;
    }
    if (t0 + 16 < T_) {
      #pragma unroll
      for (int j = 0; j < 8; ++j) {
        const int t = t0 + 16 + j;
        wA[j] = base[((size_t)t << 11) + ((c + t) & (U_ - 1))];
      }
    }
    #pragma unroll
    for (int j = 0; j < 8; ++j) {
      const int t = t0 + 8 + j;
      h = fast_tanh(fmaf(RHO_, h, wB[j]));
      base[((size_t)t << 11) + ((c + t) & (U_ - 1))] = h;
    }
  }
}

extern "C" void kernel_launch(void* const* d_in, const int* in_sizes, int n_in,
                              void* d_out, int out_size, void* d_ws, size_t ws_size,
                              hipStream_t stream) {
  const float* A    = (const float*)d_in[0];   // inputs [B,T,D_IN]
  const float* h0   = (const float*)d_in[1];   // [B,U]
  const float* W    = (const float*)d_in[2];   // kernel [D_IN,U]
  const float* bias = (const float*)d_in[3];   // [U]
  float* out = (float*)d_out;                  // [B,T,U]

  const size_t US_BYTES = (size_t)B_ * T_ * U_ * 4;          // 134,217,728
  const size_t AB_BYTES = (size_t)B_ * T_ * 256 * 2;         // 8,388,608
  const size_t WB_BYTES = (size_t)U_ * 256 * 2;              // 1,048,576
  const size_t NEEDED = US_BYTES + AB_BYTES + WB_BYTES;

  if (ws_size >= NEEDED) {
    float* us = (float*)d_ws;
    unsigned short* Ab  = (unsigned short*)((char*)d_ws + US_BYTES);
    unsigned short* Wbt = (unsigned short*)((char*)d_ws + US_BYTES + AB_BYTES);

    convert_a_kernel<<<2048, 256, 0, stream>>>(A, Ab);   // 16384 rows * 32 quads
    convert_w_kernel<<<256, 256, 0, stream>>>(W, Wbt);
    dim3 gg(U_ / 128, (B_ * T_) / 128);   // (16, 128)
    mfma_gemm3_kernel<<<gg, 256, 0, stream>>>(Ab, Wbt, bias, us);
    dim3 sg(U_ / 256, B_);                // (8, 32)
    ring_scan2_kernel<<<sg, 256, 0, stream>>>(us, h0, out);
  } else {
    dim3 gemm_grid(U_ / 64, (B_ * T_) / 64);
    gemm_bias_kernel<<<gemm_grid, 256, 0, stream>>>(A, W, bias, out);
    dim3 scan_grid(U_ / 256, B_);
    ring_scan_kernel<<<scan_grid, 256, 0, stream>>>(out, h0);
  }
}

// Round 8
// 261.953 us; speedup vs baseline: 1.2311x; 1.2311x over previous
//
#include <hip/hip_runtime.h>
#include <hip/hip_bf16.h>

#define U_ 2048
#define T_ 512
#define K_ 128
#define B_ 32
#define RHO_ 0.99f

typedef __attribute__((ext_vector_type(8))) short short8;
typedef __attribute__((ext_vector_type(4))) float f32x4;

__device__ __forceinline__ float fast_tanh(float x) {
  float e = __expf(2.0f * x);          // inf for large x -> returns +/-1 correctly
  return 1.0f - 2.0f / (e + 1.0f);
}

__device__ __forceinline__ unsigned short bf16_rne(float x) {
  unsigned int u = __float_as_uint(x);
  u += 0x7FFFu + ((u >> 16) & 1u);
  return (unsigned short)(u >> 16);
}

// ---------------- converts ----------------
// A [16384][128] fp32 -> Ab [16384][256] bf16 (k<128: hi, k>=128: lo residual)
__global__ __launch_bounds__(256) void convert_a_kernel(
    const float* __restrict__ A, unsigned short* __restrict__ Ab) {
  const int gi = blockIdx.x * 256 + threadIdx.x;
  const int m = gi >> 5;          // needs 2048 blocks
  const int kq = (gi & 31) << 2;
  const float4 v = *(const float4*)&A[(size_t)m * K_ + kq];
  ushort4 hi, lo;
  hi.x = bf16_rne(v.x); hi.y = bf16_rne(v.y); hi.z = bf16_rne(v.z); hi.w = bf16_rne(v.w);
  lo.x = bf16_rne(v.x - __uint_as_float((unsigned)hi.x << 16));
  lo.y = bf16_rne(v.y - __uint_as_float((unsigned)hi.y << 16));
  lo.z = bf16_rne(v.z - __uint_as_float((unsigned)hi.z << 16));
  lo.w = bf16_rne(v.w - __uint_as_float((unsigned)hi.w << 16));
  *(ushort4*)&Ab[(size_t)m * 256 + kq] = hi;
  *(ushort4*)&Ab[(size_t)m * 256 + 128 + kq] = lo;
}

// W [128][2048] fp32 -> Wbt [2048][256] bf16 transposed, duplicated along k
__global__ __launch_bounds__(256) void convert_w_kernel(
    const float* __restrict__ W, unsigned short* __restrict__ Wbt) {
  const int gi = blockIdx.x * 256 + threadIdx.x;   // 65536 threads
  const int kq = gi >> 11;        // 0..31
  const int n = gi & 2047;
  const int k = kq << 2;
  ushort4 w;
  w.x = bf16_rne(W[(size_t)(k + 0) * U_ + n]);
  w.y = bf16_rne(W[(size_t)(k + 1) * U_ + n]);
  w.z = bf16_rne(W[(size_t)(k + 2) * U_ + n]);
  w.w = bf16_rne(W[(size_t)(k + 3) * U_ + n]);
  *(ushort4*)&Wbt[(size_t)n * 256 + k] = w;
  *(ushort4*)&Wbt[(size_t)n * 256 + 128 + k] = w;
}

// ---------------- MFMA GEMM v4: natural-layout aligned stores ----------------
// Same K-loop as v3 (XOR-swizzled unpadded LDS, 0 bank conflicts).  Epilogue
// writes u[m][n]+bias[n] straight into d_out: each store inst covers 4 rows x
// 16 consecutive floats at 64B-aligned addresses; adjacent j-stores from the
// same block complete full 128B lines -> no write amplification / RMW.
__global__ __launch_bounds__(256, 3) void mfma_gemm4_kernel(
    const unsigned short* __restrict__ Ab, const unsigned short* __restrict__ Wbt,
    const float* __restrict__ bias, float* __restrict__ out) {
  __shared__ unsigned short As[128 * 64];   // 16 KB
  __shared__ unsigned short Bs[128 * 64];   // 16 KB
  const int tid = threadIdx.x;
  const int m0 = blockIdx.y << 7;
  const int n0 = blockIdx.x << 7;
  const int wave = tid >> 6;
  const int lane = tid & 63;
  const int r = lane & 15;        // row within 16x16 tile
  const int q = lane >> 4;        // quad
  const int mw = (wave >> 1) << 6;
  const int nw = (wave & 1) << 6;

  f32x4 acc[4][4] = {};

  // staging: wave w stages rows [32w, 32w+32) of A and B.
  const int rl8 = lane >> 3;                 // 0..7
  const int cg = lane & 7;                   // global chunk (coalesced)
  const int lchunk = cg ^ rl8;               // swizzled LDS chunk
  const int wrow0 = wave << 5;

  float4 av[4], bv4[4];
  #pragma unroll
  for (int j = 0; j < 4; ++j) {
    const int row = wrow0 + (j << 3) + rl8;
    av[j]  = *(const float4*)&Ab[((size_t)(m0 + row) << 8) + (cg << 3)];
    bv4[j] = *(const float4*)&Wbt[((size_t)(n0 + row) << 8) + (cg << 3)];
  }

  #pragma unroll
  for (int s = 0; s < 4; ++s) {
    if (s) __syncthreads();                  // LDS reads of step s-1 retired
    #pragma unroll
    for (int j = 0; j < 4; ++j) {
      const int row = wrow0 + (j << 3) + rl8;
      *(float4*)&As[(row << 6) + (lchunk << 3)] = av[j];
      *(float4*)&Bs[(row << 6) + (lchunk << 3)] = bv4[j];
    }
    __syncthreads();                         // staging visible

    if (s < 3) {                             // prefetch next K-step
      const int k0n = (s + 1) << 6;
      #pragma unroll
      for (int j = 0; j < 4; ++j) {
        const int row = wrow0 + (j << 3) + rl8;
        av[j]  = *(const float4*)&Ab[((size_t)(m0 + row) << 8) + k0n + (cg << 3)];
        bv4[j] = *(const float4*)&Wbt[((size_t)(n0 + row) << 8) + k0n + (cg << 3)];
      }
    }

    #pragma unroll
    for (int kk = 0; kk < 2; ++kk) {
      short8 af[4], bf[4];
      #pragma unroll
      for (int i = 0; i < 4; ++i) {
        const int row = mw + (i << 4) + r;
        af[i] = *(const short8*)&As[(row << 6) + ((((kk << 2) + q) ^ (row & 7)) << 3)];
      }
      #pragma unroll
      for (int j2 = 0; j2 < 4; ++j2) {
        const int row = nw + (j2 << 4) + r;
        bf[j2] = *(const short8*)&Bs[(row << 6) + ((((kk << 2) + q) ^ (row & 7)) << 3)];
      }
      #pragma unroll
      for (int i = 0; i < 4; ++i)
        #pragma unroll
        for (int j2 = 0; j2 < 4; ++j2)
          acc[i][j2] = __builtin_amdgcn_mfma_f32_16x16x32_bf16(af[i], bf[j2], acc[i][j2], 0, 0, 0);
    }
  }

  // epilogue: +bias, natural layout (D layout: col=lane&15, row=quad*4+reg)
  #pragma unroll
  for (int j = 0; j < 4; ++j) {
    const int n = n0 + nw + (j << 4) + r;
    const float bv = bias[n];
    #pragma unroll
    for (int i = 0; i < 4; ++i) {
      const int mb = m0 + mw + (i << 4) + (q << 2);
      #pragma unroll
      for (int reg = 0; reg < 4; ++reg)
        out[((size_t)(mb + reg) << 11) + n] = acc[i][j][reg] + bv;
    }
  }
}

// ---------------- in-place diagonal scan (R1, proven) ----------------
// buf holds u+bias in natural [B*T][U] layout; chain c of batch b computes
// h_t = tanh(u[t][(c+t)%U] + 0.99*h_{t-1}) in place.
__global__ __launch_bounds__(256) void ring_scan_kernel(
    float* __restrict__ buf, const float* __restrict__ h0) {
  const int b = blockIdx.y;
  const int c = (blockIdx.x << 8) + threadIdx.x;
  float* const base = buf + (size_t)b * (T_ * U_);
  float h = h0[((size_t)b << 11) + ((c + U_ - 1) & (U_ - 1))];
  float wA[8], wB[8];
  #pragma unroll
  for (int j = 0; j < 8; ++j)
    wA[j] = base[((size_t)j << 11) + ((c + j) & (U_ - 1))];
  for (int t0 = 0; t0 < T_; t0 += 16) {
    #pragma unroll
    for (int j = 0; j < 8; ++j) {
      const int t = t0 + 8 + j;
      wB[j] = base[((size_t)t << 11) + ((c + t) & (U_ - 1))];
    }
    #pragma unroll
    for (int j = 0; j < 8; ++j) {
      const int t = t0 + j;
      h = fast_tanh(fmaf(RHO_, h, wA[j]));
      base[((size_t)t << 11) + ((c + t) & (U_ - 1))] = h;
    }
    if (t0 + 16 < T_) {
      #pragma unroll
      for (int j = 0; j < 8; ++j) {
        const int t = t0 + 16 + j;
        wA[j] = base[((size_t)t << 11) + ((c + t) & (U_ - 1))];
      }
    }
    #pragma unroll
    for (int j = 0; j < 8; ++j) {
      const int t = t0 + 8 + j;
      h = fast_tanh(fmaf(RHO_, h, wB[j]));
      base[((size_t)t << 11) + ((c + t) & (U_ - 1))] = h;
    }
  }
}

// ---------------- fallback path (R1, proven correct) ----------------
__global__ __launch_bounds__(256, 4) void gemm_bias_kernel(
    const float* __restrict__ A, const float* __restrict__ W,
    const float* __restrict__ bias, float* __restrict__ out) {
  __shared__ float Asf[64][68];
  __shared__ float Bsf[64][64];
  const int tid = threadIdx.x;
  const int m0 = blockIdx.y << 6;
  const int n0 = blockIdx.x << 6;
  const int tx = tid & 15;
  const int ty = tid >> 4;
  float acc[4][4] = {};
  #pragma unroll
  for (int kb = 0; kb < 2; ++kb) {
    if (kb) __syncthreads();
    {
      const int c4 = tid & 15;
      const int r0 = tid >> 4;
      #pragma unroll
      for (int rr = 0; rr < 4; ++rr) {
        const int r = r0 + (rr << 4);
        const float4 v = *(const float4*)(A + (size_t)(m0 + r) * K_ + (kb << 6) + (c4 << 2));
        Asf[(c4 << 2) + 0][r] = v.x;
        Asf[(c4 << 2) + 1][r] = v.y;
        Asf[(c4 << 2) + 2][r] = v.z;
        Asf[(c4 << 2) + 3][r] = v.w;
      }
    }
    {
      const int c4 = tid & 15;
      const int r0 = tid >> 4;
      #pragma unroll
      for (int rr = 0; rr < 4; ++rr) {
        const int k = r0 + (rr << 4);
        *(float4*)&Bsf[k][c4 << 2] =
            *(const float4*)(W + (size_t)((kb << 6) + k) * U_ + n0 + (c4 << 2));
      }
    }
    __syncthreads();
    #pragma unroll 16
    for (int k = 0; k < 64; ++k) {
      const float4 a = *(const float4*)&Asf[k][ty << 2];
      const float4 b = *(const float4*)&Bsf[k][tx << 2];
      acc[0][0] = fmaf(a.x, b.x, acc[0][0]); acc[0][1] = fmaf(a.x, b.y, acc[0][1]);
      acc[0][2] = fmaf(a.x, b.z, acc[0][2]); acc[0][3] = fmaf(a.x, b.w, acc[0][3]);
      acc[1][0] = fmaf(a.y, b.x, acc[1][0]); acc[1][1] = fmaf(a.y, b.y, acc[1][1]);
      acc[1][2] = fmaf(a.y, b.z, acc[1][2]); acc[1][3] = fmaf(a.y, b.w, acc[1][3]);
      acc[2][0] = fmaf(a.z, b.x, acc[2][0]); acc[2][1] = fmaf(a.z, b.y, acc[2][1]);
      acc[2][2] = fmaf(a.z, b.z, acc[2][2]); acc[2][3] = fmaf(a.z, b.w, acc[2][3]);
      acc[3][0] = fmaf(a.w, b.x, acc[3][0]); acc[3][1] = fmaf(a.w, b.y, acc[3][1]);
      acc[3][2] = fmaf(a.w, b.z, acc[3][2]); acc[3][3] = fmaf(a.w, b.w, acc[3][3]);
    }
  }
  const float4 bv = *(const float4*)(bias + n0 + (tx << 2));
  #pragma unroll
  for (int i = 0; i < 4; ++i) {
    float4 o;
    o.x = acc[i][0] + bv.x; o.y = acc[i][1] + bv.y;
    o.z = acc[i][2] + bv.z; o.w = acc[i][3] + bv.w;
    *(float4*)(out + (size_t)(m0 + (ty << 2) + i) * U_ + n0 + (tx << 2)) = o;
  }
}

extern "C" void kernel_launch(void* const* d_in, const int* in_sizes, int n_in,
                              void* d_out, int out_size, void* d_ws, size_t ws_size,
                              hipStream_t stream) {
  const float* A    = (const float*)d_in[0];   // inputs [B,T,D_IN]
  const float* h0   = (const float*)d_in[1];   // [B,U]
  const float* W    = (const float*)d_in[2];   // kernel [D_IN,U]
  const float* bias = (const float*)d_in[3];   // [U]
  float* out = (float*)d_out;                  // [B,T,U]

  const size_t AB_BYTES = (size_t)B_ * T_ * 256 * 2;         // 8,388,608
  const size_t WB_BYTES = (size_t)U_ * 256 * 2;              // 1,048,576
  const size_t NEEDED = AB_BYTES + WB_BYTES;

  if (ws_size >= NEEDED) {
    unsigned short* Ab  = (unsigned short*)d_ws;
    unsigned short* Wbt = (unsigned short*)((char*)d_ws + AB_BYTES);

    convert_a_kernel<<<2048, 256, 0, stream>>>(A, Ab);   // 16384 rows * 32 quads
    convert_w_kernel<<<256, 256, 0, stream>>>(W, Wbt);
    dim3 gg(U_ / 128, (B_ * T_) / 128);   // (16, 128)
    mfma_gemm4_kernel<<<gg, 256, 0, stream>>>(Ab, Wbt, bias, out);
  } else {
    dim3 gemm_grid(U_ / 64, (B_ * T_) / 64);
    gemm_bias_kernel<<<gemm_grid, 256, 0, stream>>>(A, W, bias, out);
  }
  dim3 scan_grid(U_ / 256, B_);           // (8, 32)
  ring_scan_kernel<<<scan_grid, 256, 0, stream>>>(out, h0);
}